// Round 8
// baseline (2895.570 us; speedup 1.0000x reference)
//
#include <hip/hip_runtime.h>

// HetGTCN: 5-hop heterogeneous GNN on MI355X.
//   1. CSR build for 4 relations (hist -> shfl-scan -> scatter, packed i32x2 edges)
//   2. fc1p/fc1a: bf16 MFMA GEMM (W in registers, grid-strided node tiles)
//   3. 5 hops x 2 types: spmm2 (bf16 gather, NT streaming) -> score (bf16 MFMA)
//      -> combine (softmax beta blend)
//   4. fc2: bf16 MFMA (W2 in registers) -> d_out [Np,64] f32
// Round-7 lesson: __builtin_nontemporal_* requires ext_vector types, not
// HIP_vector_type classes (float4/int2/uint4). All 16B device traffic uses
// ext_vector typedefs now.

typedef __attribute__((ext_vector_type(8))) short bf16x8;
typedef __attribute__((ext_vector_type(4))) float f32x4;
typedef __attribute__((ext_vector_type(4))) unsigned u32x4;
typedef __attribute__((ext_vector_type(2))) int i32x2;
typedef unsigned short ushort_t;

__device__ inline unsigned short f2bf(float f) {
  union { float f; unsigned u; } x; x.f = f;
  unsigned r = x.u + 0x7fff + ((x.u >> 16) & 1);   // RNE
  return (unsigned short)(r >> 16);
}
__device__ inline float bf2f(unsigned short u) {
  union { unsigned u; float f; } x; x.u = (unsigned)u << 16; return x.f;
}
__device__ inline float i2f(int i) {
  union { int i; float f; } x; x.i = i; return x.f;
}
__device__ inline int f2i(float f) {
  union { float f; int i; } x; x.f = f; return x.i;
}
__device__ inline void unpack8(u32x4 u, float* f) {
  union { unsigned u; float f; } c;
  c.u = u.x << 16;          f[0] = c.f;
  c.u = u.x & 0xffff0000u;  f[1] = c.f;
  c.u = u.y << 16;          f[2] = c.f;
  c.u = u.y & 0xffff0000u;  f[3] = c.f;
  c.u = u.z << 16;          f[4] = c.f;
  c.u = u.z & 0xffff0000u;  f[5] = c.f;
  c.u = u.w << 16;          f[6] = c.f;
  c.u = u.w & 0xffff0000u;  f[7] = c.f;
}
__device__ inline u32x4 pack8(const float* f) {
  u32x4 u;
  u.x = (unsigned)f2bf(f[0]) | ((unsigned)f2bf(f[1]) << 16);
  u.y = (unsigned)f2bf(f[2]) | ((unsigned)f2bf(f[3]) << 16);
  u.z = (unsigned)f2bf(f[4]) | ((unsigned)f2bf(f[5]) << 16);
  u.w = (unsigned)f2bf(f[6]) | ((unsigned)f2bf(f[7]) << 16);
  return u;
}

__global__ void zero_kernel(float* __restrict__ p, int n) {
  int i = blockIdx.x * blockDim.x + threadIdx.x;
  if (i < n) p[i] = 0.f;
}

__global__ void hist_kernel(const int* __restrict__ dst, int E, int* __restrict__ cnt) {
  int i = blockIdx.x * blockDim.x + threadIdx.x;
  if (i < E) atomicAdd(&cnt[dst[i]], 1);
}

// One block (1024 threads) per relation; shfl wave-scan, 3 barriers per 1024-chunk.
__global__ void scan4_kernel(const int* __restrict__ cnt, int* __restrict__ rp,
                             int* __restrict__ cur, int Np, int Na) {
  __shared__ int wsum[16];
  __shared__ int carry_s;
  int r = blockIdx.x;
  int N = (r < 2) ? Np : Na;
  size_t coff  = (r==0)?0 : (r==1)? (size_t)Np : (r==2)? (size_t)2*Np : (size_t)2*Np+Na;
  size_t rpoff = (r==0)?0 : (r==1)? (size_t)(Np+1) : (r==2)? (size_t)2*(Np+1) : (size_t)2*(Np+1)+(Na+1);
  const int* c = cnt + coff;
  int* rpp = rp + rpoff;
  int* cpp = cur + coff;
  int tid = threadIdx.x;
  int lane = tid & 63, wv = tid >> 6;
  if (tid == 0) carry_s = 0;
  for (int base = 0; base < N; base += 1024) {
    int i = base + tid;
    int v = (i < N) ? c[i] : 0;
    int s = v;
#pragma unroll
    for (int off = 1; off < 64; off <<= 1) {
      int t = __shfl_up(s, off);
      if (lane >= off) s += t;
    }
    if (lane == 63) wsum[wv] = s;
    __syncthreads();
    if (wv == 0 && lane < 16) {
      int p = wsum[lane];
      int q = p;
#pragma unroll
      for (int off = 1; off < 16; off <<= 1) {
        int t = __shfl_up(q, off);
        if (lane >= off) q += t;
      }
      wsum[lane] = q - p;   // exclusive wave prefix
    }
    __syncthreads();
    int carry = carry_s;
    int wexcl = wsum[wv];
    int excl = carry + wexcl + (s - v);
    if (i < N) { rpp[i] = excl; cpp[i] = excl; }
    int mytotal = wexcl + s;
    __syncthreads();
    if (tid == 1023) carry_s = carry + mytotal;
  }
  __syncthreads();
  if (tid == 0) rpp[N] = carry_s;
}

// Scatter edges into packed (col, w_bits) i32x2 CSR slots.
__global__ void scatter_kernel(const int* __restrict__ src, const int* __restrict__ dst,
                               const float* __restrict__ w, int* __restrict__ cur,
                               i32x2* __restrict__ cw, int E) {
  int i = blockIdx.x * blockDim.x + threadIdx.x;
  if (i < E) {
    int p = atomicAdd(&cur[dst[i]], 1);
    i32x2 v; v.x = src[i]; v.y = f2i(w[i]);
    cw[p] = v;
  }
}

// fc1 via bf16 MFMA: relu(x @ W + b) -> bf16 o1 (x table) and o2 (h table).
template<int K, int KH>
__global__ __launch_bounds__(256) void fc1_mfma_kernel(
    const float* __restrict__ x, const float* __restrict__ W,
    const float* __restrict__ b, ushort_t* __restrict__ o1, ushort_t* __restrict__ o2,
    int N) {
  constexpr int TPB = 4 / KH;
  __shared__ float cstage[4][16][128];   // 32 KB
  int tid = threadIdx.x;
  int lane = tid & 63, wid = tid >> 6;
  int tile = (KH == 2) ? (wid >> 1) : wid;
  int khalf = (KH == 2) ? (wid & 1) : 0;
  int r = lane & 15, kg = lane >> 4;
  bf16x8 bfr[8][4];
#pragma unroll
  for (int jt = 0; jt < 8; jt++) {
    int j = jt * 16 + r;
#pragma unroll
    for (int kt = 0; kt < 4; kt++) {
      int k0 = khalf * 128 + kt * 32 + kg * 8;
      bf16x8 v;
#pragma unroll
      for (int t = 0; t < 8; t++) v[t] = (short)f2bf(W[(size_t)(k0 + t) * 128 + j]);
      bfr[jt][kt] = v;
    }
  }
  float bb[8];
  {
    int j0 = (tid & 15) * 8;
#pragma unroll
    for (int t = 0; t < 8; t++) bb[t] = b[j0 + t];
  }
  int ntiles = (N + 15) >> 4;
  int tstride = gridDim.x * TPB;
  for (int tb = blockIdx.x * TPB; tb < ntiles; tb += tstride) {
    int mytile = tb + tile;
    int nodeA = mytile * 16 + r;
    if (nodeA >= N) nodeA = 0;
    const float* xrow = x + (size_t)nodeA * K + khalf * 128;
    bf16x8 afr[4];
#pragma unroll
    for (int kt = 0; kt < 4; kt++) {
      const f32x4* p = (const f32x4*)(xrow + kt * 32 + kg * 8);
      f32x4 lo = __builtin_nontemporal_load(p);
      f32x4 hi = __builtin_nontemporal_load(p + 1);
      bf16x8 v;
      v[0] = (short)f2bf(lo.x); v[1] = (short)f2bf(lo.y);
      v[2] = (short)f2bf(lo.z); v[3] = (short)f2bf(lo.w);
      v[4] = (short)f2bf(hi.x); v[5] = (short)f2bf(hi.y);
      v[6] = (short)f2bf(hi.z); v[7] = (short)f2bf(hi.w);
      afr[kt] = v;
    }
    f32x4 acc[8];
#pragma unroll
    for (int jt = 0; jt < 8; jt++) acc[jt] = (f32x4){0.f, 0.f, 0.f, 0.f};
#pragma unroll
    for (int jt = 0; jt < 8; jt++)
#pragma unroll
      for (int kt = 0; kt < 4; kt++)
        acc[jt] = __builtin_amdgcn_mfma_f32_16x16x32_bf16(afr[kt], bfr[jt][kt], acc[jt], 0, 0, 0);
#pragma unroll
    for (int jt = 0; jt < 8; jt++)
#pragma unroll
      for (int reg = 0; reg < 4; reg++)
        cstage[wid][kg * 4 + reg][jt * 16 + r] = acc[jt][reg];
    __syncthreads();
    int node = tid >> 4, j0 = (tid & 15) * 8;
#pragma unroll
    for (int it = 0; it < TPB; it++) {
      int n = (tb + it) * 16 + node;
      float f[8];
#pragma unroll
      for (int t = 0; t < 8; t++) {
        float v = cstage[it * KH][node][j0 + t];
        if (KH == 2) v += cstage[it * 2 + 1][node][j0 + t];
        f[t] = fmaxf(v + bb[t], 0.f);
      }
      if (n < N) {
        u32x4 pk = pack8(f);
        *(u32x4*)(o1 + (size_t)n * 128 + j0) = pk;
        *(u32x4*)(o2 + (size_t)n * 128 + j0) = pk;
      }
    }
    __syncthreads();
  }
}

// Wave-per-node SPMM over 2 relations, bf16 rows (256B): 16 lanes x 16B per row.
// 16 edges per wave-iteration (4 per 16-lane slot). Edge stream + rel output are
// nontemporal so the h-table gathers own L2.
__global__ __launch_bounds__(256) void spmm2_kernel(
    const ushort_t* __restrict__ xself,
    const float* __restrict__ d0, const float* __restrict__ d1,
    const ushort_t* __restrict__ h0, const ushort_t* __restrict__ h1,
    const int* __restrict__ rp0, const i32x2* __restrict__ cw0,
    const int* __restrict__ rp1, const i32x2* __restrict__ cw1,
    ushort_t* __restrict__ rel, int N) {
  int tid = threadIdx.x;
  int lane = tid & 63, wid = tid >> 6;
  int fg = lane & 15;
  int eslot = lane >> 4;
  int n = blockIdx.x * 4 + wid;
  if (n >= N) return;
  float xf[8];
  unpack8(*(const u32x4*)(xself + (size_t)n * 128 + fg * 8), xf);
#pragma unroll
  for (int srel = 0; srel < 2; srel++) {
    const float sd = srel ? d1[n] : d0[n];
    const int* rp = srel ? rp1 : rp0;
    const i32x2* cw = srel ? cw1 : cw0;
    const ushort_t* h = srel ? h1 : h0;
    float acc[8];
#pragma unroll
    for (int t = 0; t < 8; t++) acc[t] = 0.f;
    int beg = rp[n], end = rp[n + 1];
    for (int cb = beg; cb < end; cb += 64) {
      int m = end - cb; if (m > 64) m = 64;
      int creg = 0, wbits = 0;
      if (lane < m) {
        i32x2 p = __builtin_nontemporal_load(&cw[cb + lane]);
        creg = p.x; wbits = p.y;
      }
      int i = 0;
      for (; i + 16 <= m; i += 16) {
        int e0 = i + eslot, e1 = i + 4 + eslot, e2 = i + 8 + eslot, e3 = i + 12 + eslot;
        int   c0 = __shfl(creg, e0), c1 = __shfl(creg, e1);
        int   c2 = __shfl(creg, e2), c3 = __shfl(creg, e3);
        float v0 = i2f(__shfl(wbits, e0)), v1 = i2f(__shfl(wbits, e1));
        float v2 = i2f(__shfl(wbits, e2)), v3 = i2f(__shfl(wbits, e3));
        u32x4 g0 = *(const u32x4*)(h + (size_t)c0 * 128 + fg * 8);
        u32x4 g1 = *(const u32x4*)(h + (size_t)c1 * 128 + fg * 8);
        u32x4 g2 = *(const u32x4*)(h + (size_t)c2 * 128 + fg * 8);
        u32x4 g3 = *(const u32x4*)(h + (size_t)c3 * 128 + fg * 8);
        float hf[8];
        unpack8(g0, hf);
#pragma unroll
        for (int t = 0; t < 8; t++) acc[t] = fmaf(v0, hf[t], acc[t]);
        unpack8(g1, hf);
#pragma unroll
        for (int t = 0; t < 8; t++) acc[t] = fmaf(v1, hf[t], acc[t]);
        unpack8(g2, hf);
#pragma unroll
        for (int t = 0; t < 8; t++) acc[t] = fmaf(v2, hf[t], acc[t]);
        unpack8(g3, hf);
#pragma unroll
        for (int t = 0; t < 8; t++) acc[t] = fmaf(v3, hf[t], acc[t]);
      }
      for (; i < m; i += 4) {
        int e = i + eslot;
        int   c = __shfl(creg, e & 63);
        float v = i2f(__shfl(wbits, e & 63));
        if (e < m) {
          u32x4 g = *(const u32x4*)(h + (size_t)c * 128 + fg * 8);
          float hf[8];
          unpack8(g, hf);
#pragma unroll
          for (int t = 0; t < 8; t++) acc[t] = fmaf(v, hf[t], acc[t]);
        }
      }
    }
#pragma unroll
    for (int t = 0; t < 8; t++) {
      acc[t] += __shfl_xor(acc[t], 16);
      acc[t] += __shfl_xor(acc[t], 32);
    }
    if (eslot == 0) {
#pragma unroll
      for (int t = 0; t < 8; t++) acc[t] = fmaf(sd, xf[t], acc[t]);
      __builtin_nontemporal_store(pack8(acc),
          (u32x4*)(rel + (size_t)n * 256 + srel * 128 + fg * 8));
    }
  }
}

// HAN scores via bf16 MFMA. W1 held in registers as B-frags; A-frags NT bf16 loads.
__global__ __launch_bounds__(256) void score_mfma_kernel(
    const ushort_t* __restrict__ rel,   // [N,2,128] bf16
    const float* __restrict__ W1,       // [128,128] (k-major)
    const float* __restrict__ b1, const float* __restrict__ w2,
    float* __restrict__ s_out, int N, int nwaves) {
  int tid = threadIdx.x;
  int lane = tid & 63;
  int gw = blockIdx.x * 4 + (tid >> 6);
  int r = lane & 15;
  int kg = lane >> 4;
  bf16x8 bfr[8][4];
#pragma unroll
  for (int jt = 0; jt < 8; jt++) {
    int j = jt * 16 + r;
#pragma unroll
    for (int kt = 0; kt < 4; kt++) {
      int k0 = kt * 32 + kg * 8;
      bf16x8 v;
#pragma unroll
      for (int t = 0; t < 8; t++) v[t] = (short)f2bf(W1[(size_t)(k0 + t) * 128 + j]);
      bfr[jt][kt] = v;
    }
  }
  float b1v[8], w2v[8];
#pragma unroll
  for (int jt = 0; jt < 8; jt++) { b1v[jt] = b1[jt * 16 + r]; w2v[jt] = w2[jt * 16 + r]; }
  float s0 = 0.f, s1 = 0.f;
  int ntiles = (N + 15) >> 4;
  for (int tile = gw; tile < ntiles; tile += nwaves) {
    int n0 = tile * 16;
    int nodeA = n0 + r;
    size_t base = (size_t)((nodeA < N) ? nodeA : 0) * 256;
#pragma unroll
    for (int sub = 0; sub < 2; sub++) {
      bf16x8 afr[4];
#pragma unroll
      for (int kt = 0; kt < 4; kt++)
        afr[kt] = __builtin_nontemporal_load(
            (const bf16x8*)(rel + base + sub * 128 + kt * 32 + kg * 8));
      f32x4 acc[8];
#pragma unroll
      for (int jt = 0; jt < 8; jt++) acc[jt] = (f32x4){0.f, 0.f, 0.f, 0.f};
#pragma unroll
      for (int jt = 0; jt < 8; jt++)
#pragma unroll
        for (int kt = 0; kt < 4; kt++)
          acc[jt] = __builtin_amdgcn_mfma_f32_16x16x32_bf16(afr[kt], bfr[jt][kt], acc[jt], 0, 0, 0);
      float sacc = 0.f;
#pragma unroll
      for (int jt = 0; jt < 8; jt++) {
#pragma unroll
        for (int reg = 0; reg < 4; reg++) {
          int nm = n0 + kg * 4 + reg;
          if (nm < N) sacc += w2v[jt] * tanhf(acc[jt][reg] + b1v[jt]);
        }
      }
      if (sub == 0) s0 += sacc; else s1 += sacc;
    }
  }
#pragma unroll
  for (int m = 32; m >= 1; m >>= 1) { s0 += __shfl_xor(s0, m); s1 += __shfl_xor(s1, m); }
  if (lane == 0) { atomicAdd(&s_out[0], s0); atomicAdd(&s_out[1], s1); }
}

// h[n,:] = beta0*rel[n,0,:] + beta1*rel[n,1,:]; NT rel reads, cached h store.
__global__ void combine_kernel(const ushort_t* __restrict__ rel, const float* __restrict__ s,
                               ushort_t* __restrict__ h, int N, float invN) {
  int i = blockIdx.x * blockDim.x + threadIdx.x;
  if (i >= N * 16) return;
  float m0 = s[0] * invN, m1 = s[1] * invN;
  float mx = fmaxf(m0, m1);
  float e0 = expf(m0 - mx), e1 = expf(m1 - mx);
  float inv = 1.f / (e0 + e1);
  float be0 = e0 * inv, be1 = e1 * inv;
  int n = i >> 4, q = i & 15;
  float f0[8], f1[8], o[8];
  unpack8(__builtin_nontemporal_load((const u32x4*)(rel + (size_t)n * 256 + q * 8)), f0);
  unpack8(__builtin_nontemporal_load((const u32x4*)(rel + (size_t)n * 256 + 128 + q * 8)), f1);
#pragma unroll
  for (int t = 0; t < 8; t++) o[t] = be0 * f0[t] + be1 * f1[t];
  *(u32x4*)(h + (size_t)n * 128 + q * 8) = pack8(o);
}

// fc2 via bf16 MFMA: out = h @ W2(128x64) + b2.
__global__ __launch_bounds__(256) void fc2_mfma_kernel(
    const ushort_t* __restrict__ h,     // [N,128] bf16
    const float* __restrict__ W,        // [128,64]
    const float* __restrict__ b,        // [64]
    float* __restrict__ out, int N, int nwaves) {
  int tid = threadIdx.x;
  int lane = tid & 63;
  int gw = blockIdx.x * 4 + (tid >> 6);
  int r = lane & 15, kg = lane >> 4;
  bf16x8 bfr[4][4];
#pragma unroll
  for (int jt = 0; jt < 4; jt++) {
    int j = jt * 16 + r;
#pragma unroll
    for (int kt = 0; kt < 4; kt++) {
      int k0 = kt * 32 + kg * 8;
      bf16x8 v;
#pragma unroll
      for (int t = 0; t < 8; t++) v[t] = (short)f2bf(W[(size_t)(k0 + t) * 64 + j]);
      bfr[jt][kt] = v;
    }
  }
  float bv[4];
#pragma unroll
  for (int jt = 0; jt < 4; jt++) bv[jt] = b[jt * 16 + r];
  int ntiles = (N + 15) >> 4;
  for (int tile = gw; tile < ntiles; tile += nwaves) {
    int n0 = tile * 16;
    int nodeA = n0 + r;
    const ushort_t* hrow = h + (size_t)((nodeA < N) ? nodeA : 0) * 128;
    bf16x8 afr[4];
#pragma unroll
    for (int kt = 0; kt < 4; kt++)
      afr[kt] = *(const bf16x8*)(hrow + kt * 32 + kg * 8);
    f32x4 acc[4];
#pragma unroll
    for (int jt = 0; jt < 4; jt++) acc[jt] = (f32x4){0.f, 0.f, 0.f, 0.f};
#pragma unroll
    for (int jt = 0; jt < 4; jt++)
#pragma unroll
      for (int kt = 0; kt < 4; kt++)
        acc[jt] = __builtin_amdgcn_mfma_f32_16x16x32_bf16(afr[kt], bfr[jt][kt], acc[jt], 0, 0, 0);
#pragma unroll
    for (int jt = 0; jt < 4; jt++)
#pragma unroll
      for (int reg = 0; reg < 4; reg++) {
        int n = n0 + kg * 4 + reg;
        if (n < N) out[(size_t)n * 64 + jt * 16 + r] = acc[jt][reg] + bv[jt];
      }
  }
}

extern "C" void kernel_launch(void* const* d_in, const int* in_sizes, int n_in,
                              void* d_out, int out_size, void* d_ws, size_t ws_size,
                              hipStream_t stream) {
  const float* x_paper  = (const float*)d_in[0];
  const float* x_author = (const float*)d_in[1];
  const float* fc1p_W = (const float*)d_in[2];
  const float* fc1p_b = (const float*)d_in[3];
  const float* fc1a_W = (const float*)d_in[4];
  const float* fc1a_b = (const float*)d_in[5];
  const float* fc2_W  = (const float*)d_in[6];
  const float* fc2_b  = (const float*)d_in[7];
  const float* semW1  = (const float*)d_in[8];
  const float* semb1  = (const float*)d_in[9];
  const float* semw2  = (const float*)d_in[10];
  const float* d_pp = (const float*)d_in[11];
  const float* d_pa = (const float*)d_in[12];
  const float* d_ap = (const float*)d_in[13];
  const float* d_aa = (const float*)d_in[14];
  const float* w_pp = (const float*)d_in[15];
  const float* w_pa = (const float*)d_in[16];
  const float* w_ap = (const float*)d_in[17];
  const float* w_aa = (const float*)d_in[18];
  const int* src_pp = (const int*)d_in[19];
  const int* dst_pp = (const int*)d_in[20];
  const int* src_pa = (const int*)d_in[21];
  const int* dst_pa = (const int*)d_in[22];
  const int* src_ap = (const int*)d_in[23];
  const int* dst_ap = (const int*)d_in[24];
  const int* src_aa = (const int*)d_in[25];
  const int* dst_aa = (const int*)d_in[26];

  const int Np = in_sizes[11];
  const int Na = in_sizes[13];
  const int E[4] = { in_sizes[15], in_sizes[16], in_sizes[17], in_sizes[18] };
  const int Nmax = (Np > Na) ? Np : Na;

  char* base = (char*)d_ws;
  size_t off = 0;
  ushort_t* xp = (ushort_t*)(base + off); off += (size_t)Np * 128 * 2;
  ushort_t* xa = (ushort_t*)(base + off); off += (size_t)Na * 128 * 2;
  ushort_t* hp = (ushort_t*)(base + off); off += (size_t)Np * 128 * 2;
  ushort_t* ha = (ushort_t*)(base + off); off += (size_t)Na * 128 * 2;
  ushort_t* rel = (ushort_t*)(base + off); off += (size_t)Nmax * 256 * 2;
  float* ssum = (float*)(base + off); off += 32 * 4;
  int* cnt  = (int*)(base + off); off += (size_t)(2 * Np + 2 * Na) * 4;
  int* rpB  = (int*)(base + off); off += (size_t)(2 * (Np + 1) + 2 * (Na + 1)) * 4;
  int* curB = (int*)(base + off); off += (size_t)(2 * Np + 2 * Na) * 4;
  size_t Esum = (size_t)E[0] + E[1] + E[2] + E[3];
  off = (off + 15) & ~(size_t)15;
  i32x2* cwB = (i32x2*)(base + off); off += Esum * 8;
  (void)ws_size; (void)n_in; (void)out_size;

  int* cnt_r[4] = { cnt, cnt + Np, cnt + (size_t)2 * Np, cnt + (size_t)2 * Np + Na };
  int* rp_r[4]  = { rpB, rpB + (Np + 1), rpB + (size_t)2 * (Np + 1),
                    rpB + (size_t)2 * (Np + 1) + (Na + 1) };
  int* cur_r[4] = { curB, curB + Np, curB + (size_t)2 * Np, curB + (size_t)2 * Np + Na };
  size_t eoff[4] = { 0, (size_t)E[0], (size_t)E[0] + E[1], (size_t)E[0] + E[1] + E[2] };
  i32x2* cw_r[4];
  for (int r = 0; r < 4; r++) cw_r[r] = cwB + eoff[r];

  const int* srcs[4]    = { src_pp, src_pa, src_ap, src_aa };
  const int* dsts[4]    = { dst_pp, dst_pa, dst_ap, dst_aa };
  const float* wedge[4] = { w_pp, w_pa, w_ap, w_aa };

  int Z = 32 + 2 * Np + 2 * Na;
  zero_kernel<<<(Z + 255) / 256, 256, 0, stream>>>(ssum, Z);

  for (int r = 0; r < 4; r++)
    hist_kernel<<<(E[r] + 255) / 256, 256, 0, stream>>>(dsts[r], E[r], cnt_r[r]);
  scan4_kernel<<<4, 1024, 0, stream>>>(cnt, rpB, curB, Np, Na);
  for (int r = 0; r < 4; r++)
    scatter_kernel<<<(E[r] + 255) / 256, 256, 0, stream>>>(srcs[r], dsts[r], wedge[r],
                                                           cur_r[r], cw_r[r], E[r]);

  fc1_mfma_kernel<256, 2><<<256, 256, 0, stream>>>(x_paper, fc1p_W, fc1p_b, xp, hp, Np);
  fc1_mfma_kernel<128, 1><<<256, 256, 0, stream>>>(x_author, fc1a_W, fc1a_b, xa, ha, Na);

  const int SCORE_BLOCKS = 256;
  const int SCORE_WAVES = SCORE_BLOCKS * 4;

  for (int i = 0; i < 5; i++) {
    // paper: pp (gather h_p), pa (gather h_a)
    float* sp = ssum + (size_t)(i * 2 + 0) * 2;
    spmm2_kernel<<<(Np + 3) / 4, 256, 0, stream>>>(xp, d_pp, d_pa, hp, ha,
        rp_r[0], cw_r[0], rp_r[1], cw_r[1], rel, Np);
    score_mfma_kernel<<<SCORE_BLOCKS, 256, 0, stream>>>(rel,
        semW1 + (size_t)(i * 2 + 0) * 16384, semb1 + (size_t)(i * 2 + 0) * 128,
        semw2 + (size_t)(i * 2 + 0) * 128, sp, Np, SCORE_WAVES);
    combine_kernel<<<(Np * 16 + 255) / 256, 256, 0, stream>>>(rel, sp, hp, Np, 1.f / Np);

    // author: ap (gather new h_p), aa (gather h_a)
    float* sa = ssum + (size_t)(i * 2 + 1) * 2;
    spmm2_kernel<<<(Na + 3) / 4, 256, 0, stream>>>(xa, d_ap, d_aa, hp, ha,
        rp_r[2], cw_r[2], rp_r[3], cw_r[3], rel, Na);
    score_mfma_kernel<<<SCORE_BLOCKS, 256, 0, stream>>>(rel,
        semW1 + (size_t)(i * 2 + 1) * 16384, semb1 + (size_t)(i * 2 + 1) * 128,
        semw2 + (size_t)(i * 2 + 1) * 128, sa, Na, SCORE_WAVES);
    combine_kernel<<<(Na * 16 + 255) / 256, 256, 0, stream>>>(rel, sa, ha, Na, 1.f / Na);
  }

  fc2_mfma_kernel<<<256, 256, 0, stream>>>(hp, fc2_W, fc2_b, (float*)d_out, Np, 1024);
}

// Round 9
// 2508.481 us; speedup vs baseline: 1.1543x; 1.1543x over previous
//
#include <hip/hip_runtime.h>

// HetGTCN: 5-hop heterogeneous GNN on MI355X.
//   1. CSR build: zero -> hist4 (merged) -> scan -> build_kernel (scatter4 + fc1p + fc1a fused)
//   2. 5 hops x 2 types: spmm2 (bf16 gather, NT streaming) -> score (bf16 MFMA) -> combine
//      (author pipeline SKIPPED at final hop: its output is dead, matching JAX DCE)
//   3. fc2: bf16 MFMA -> d_out [Np,64] f32
// Round-8 lessons: scatter is random-write service-rate bound (8x write amplification,
// VALUBusy 0.3%) -> fuse independent MFMA fc1 work into the same dispatch to overlap.

typedef __attribute__((ext_vector_type(8))) short bf16x8;
typedef __attribute__((ext_vector_type(4))) float f32x4;
typedef __attribute__((ext_vector_type(4))) unsigned u32x4;
typedef __attribute__((ext_vector_type(2))) int i32x2;
typedef unsigned short ushort_t;

__device__ inline unsigned short f2bf(float f) {
  union { float f; unsigned u; } x; x.f = f;
  unsigned r = x.u + 0x7fff + ((x.u >> 16) & 1);   // RNE
  return (unsigned short)(r >> 16);
}
__device__ inline float i2f(int i) {
  union { int i; float f; } x; x.i = i; return x.f;
}
__device__ inline int f2i(float f) {
  union { float f; int i; } x; x.f = f; return x.i;
}
__device__ inline void unpack8(u32x4 u, float* f) {
  union { unsigned u; float f; } c;
  c.u = u.x << 16;          f[0] = c.f;
  c.u = u.x & 0xffff0000u;  f[1] = c.f;
  c.u = u.y << 16;          f[2] = c.f;
  c.u = u.y & 0xffff0000u;  f[3] = c.f;
  c.u = u.z << 16;          f[4] = c.f;
  c.u = u.z & 0xffff0000u;  f[5] = c.f;
  c.u = u.w << 16;          f[6] = c.f;
  c.u = u.w & 0xffff0000u;  f[7] = c.f;
}
__device__ inline u32x4 pack8(const float* f) {
  u32x4 u;
  u.x = (unsigned)f2bf(f[0]) | ((unsigned)f2bf(f[1]) << 16);
  u.y = (unsigned)f2bf(f[2]) | ((unsigned)f2bf(f[3]) << 16);
  u.z = (unsigned)f2bf(f[4]) | ((unsigned)f2bf(f[5]) << 16);
  u.w = (unsigned)f2bf(f[6]) | ((unsigned)f2bf(f[7]) << 16);
  return u;
}

__global__ void zero_kernel(float* __restrict__ p, int n) {
  int i = blockIdx.x * blockDim.x + threadIdx.x;
  if (i < n) p[i] = 0.f;
}

struct Hist4Args {
  const int* dst[4];
  int* cnt[4];
  int E[4];
  int nb[4];
};

__global__ void hist4_kernel(Hist4Args a) {
  int vb = blockIdx.x;
#pragma unroll
  for (int r = 0; r < 4; r++) {
    if (vb < a.nb[r]) {
      int i = vb * 256 + threadIdx.x;
      if (i < a.E[r]) atomicAdd(&a.cnt[r][a.dst[r][i]], 1);
      return;
    }
    vb -= a.nb[r];
  }
}

// One block (1024 threads) per relation; shfl wave-scan, 3 barriers per 1024-chunk.
__global__ void scan4_kernel(const int* __restrict__ cnt, int* __restrict__ rp,
                             int* __restrict__ cur, int Np, int Na) {
  __shared__ int wsum[16];
  __shared__ int carry_s;
  int r = blockIdx.x;
  int N = (r < 2) ? Np : Na;
  size_t coff  = (r==0)?0 : (r==1)? (size_t)Np : (r==2)? (size_t)2*Np : (size_t)2*Np+Na;
  size_t rpoff = (r==0)?0 : (r==1)? (size_t)(Np+1) : (r==2)? (size_t)2*(Np+1) : (size_t)2*(Np+1)+(Na+1);
  const int* c = cnt + coff;
  int* rpp = rp + rpoff;
  int* cpp = cur + coff;
  int tid = threadIdx.x;
  int lane = tid & 63, wv = tid >> 6;
  if (tid == 0) carry_s = 0;
  for (int base = 0; base < N; base += 1024) {
    int i = base + tid;
    int v = (i < N) ? c[i] : 0;
    int s = v;
#pragma unroll
    for (int off = 1; off < 64; off <<= 1) {
      int t = __shfl_up(s, off);
      if (lane >= off) s += t;
    }
    if (lane == 63) wsum[wv] = s;
    __syncthreads();
    if (wv == 0 && lane < 16) {
      int p = wsum[lane];
      int q = p;
#pragma unroll
      for (int off = 1; off < 16; off <<= 1) {
        int t = __shfl_up(q, off);
        if (lane >= off) q += t;
      }
      wsum[lane] = q - p;   // exclusive wave prefix
    }
    __syncthreads();
    int carry = carry_s;
    int wexcl = wsum[wv];
    int excl = carry + wexcl + (s - v);
    if (i < N) { rpp[i] = excl; cpp[i] = excl; }
    int mytotal = wexcl + s;
    __syncthreads();
    if (tid == 1023) carry_s = carry + mytotal;
  }
  __syncthreads();
  if (tid == 0) rpp[N] = carry_s;
}

// fc1 body via bf16 MFMA: relu(x @ W + b) -> bf16 o1 (x table) and o2 (h table).
template<int K, int KH>
__device__ void fc1_body(float (*cstage)[16][128],
    const float* __restrict__ x, const float* __restrict__ W,
    const float* __restrict__ b, ushort_t* __restrict__ o1, ushort_t* __restrict__ o2,
    int N, int bid, int nblocks) {
  constexpr int TPB = 4 / KH;
  int tid = threadIdx.x;
  int lane = tid & 63, wid = tid >> 6;
  int tile = (KH == 2) ? (wid >> 1) : wid;
  int khalf = (KH == 2) ? (wid & 1) : 0;
  int r = lane & 15, kg = lane >> 4;
  bf16x8 bfr[8][4];
#pragma unroll
  for (int jt = 0; jt < 8; jt++) {
    int j = jt * 16 + r;
#pragma unroll
    for (int kt = 0; kt < 4; kt++) {
      int k0 = khalf * 128 + kt * 32 + kg * 8;
      bf16x8 v;
#pragma unroll
      for (int t = 0; t < 8; t++) v[t] = (short)f2bf(W[(size_t)(k0 + t) * 128 + j]);
      bfr[jt][kt] = v;
    }
  }
  float bb[8];
  {
    int j0 = (tid & 15) * 8;
#pragma unroll
    for (int t = 0; t < 8; t++) bb[t] = b[j0 + t];
  }
  int ntiles = (N + 15) >> 4;
  int tstride = nblocks * TPB;
  for (int tb = bid * TPB; tb < ntiles; tb += tstride) {
    int mytile = tb + tile;
    int nodeA = mytile * 16 + r;
    if (nodeA >= N) nodeA = 0;
    const float* xrow = x + (size_t)nodeA * K + khalf * 128;
    bf16x8 afr[4];
#pragma unroll
    for (int kt = 0; kt < 4; kt++) {
      const f32x4* p = (const f32x4*)(xrow + kt * 32 + kg * 8);
      f32x4 lo = __builtin_nontemporal_load(p);
      f32x4 hi = __builtin_nontemporal_load(p + 1);
      bf16x8 v;
      v[0] = (short)f2bf(lo.x); v[1] = (short)f2bf(lo.y);
      v[2] = (short)f2bf(lo.z); v[3] = (short)f2bf(lo.w);
      v[4] = (short)f2bf(hi.x); v[5] = (short)f2bf(hi.y);
      v[6] = (short)f2bf(hi.z); v[7] = (short)f2bf(hi.w);
      afr[kt] = v;
    }
    f32x4 acc[8];
#pragma unroll
    for (int jt = 0; jt < 8; jt++) acc[jt] = (f32x4){0.f, 0.f, 0.f, 0.f};
#pragma unroll
    for (int jt = 0; jt < 8; jt++)
#pragma unroll
      for (int kt = 0; kt < 4; kt++)
        acc[jt] = __builtin_amdgcn_mfma_f32_16x16x32_bf16(afr[kt], bfr[jt][kt], acc[jt], 0, 0, 0);
#pragma unroll
    for (int jt = 0; jt < 8; jt++)
#pragma unroll
      for (int reg = 0; reg < 4; reg++)
        cstage[wid][kg * 4 + reg][jt * 16 + r] = acc[jt][reg];
    __syncthreads();
    int node = tid >> 4, j0 = (tid & 15) * 8;
#pragma unroll
    for (int it = 0; it < TPB; it++) {
      int n = (tb + it) * 16 + node;
      float f[8];
#pragma unroll
      for (int t = 0; t < 8; t++) {
        float v = cstage[it * KH][node][j0 + t];
        if (KH == 2) v += cstage[it * 2 + 1][node][j0 + t];
        f[t] = fmaxf(v + bb[t], 0.f);
      }
      if (n < N) {
        u32x4 pk = pack8(f);
        *(u32x4*)(o1 + (size_t)n * 128 + j0) = pk;
        *(u32x4*)(o2 + (size_t)n * 128 + j0) = pk;
      }
    }
    __syncthreads();
  }
}

__device__ void scatter_body(const int* __restrict__ src, const int* __restrict__ dst,
                             const float* __restrict__ w, int* __restrict__ cur,
                             i32x2* __restrict__ cw, int E, int bid) {
  int i = bid * 256 + threadIdx.x;
  if (i < E) {
    int p = atomicAdd(&cur[dst[i]], 1);
    i32x2 v; v.x = src[i]; v.y = f2i(w[i]);
    cw[p] = v;
  }
}

struct BuildArgs {
  // fc1 paper / author
  const float* fx[2]; const float* fW[2]; const float* fb[2];
  ushort_t* fo1[2]; ushort_t* fo2[2];
  int fN[2]; int fB[2];
  // scatter, 4 relations
  const int* src[4]; const int* dst[4]; const float* w[4];
  int* cur[4]; i32x2* cw[4];
  int E[4]; int nb[4];
};

// Fused build kernel: fc1p + fc1a (MFMA) overlap scatter4 (random-write bound).
__global__ __launch_bounds__(256) void build_kernel(BuildArgs a) {
  __shared__ float cstage[4][16][128];   // used only by fc1 blocks
  int vb = blockIdx.x;
  if (vb < a.fB[0]) {
    fc1_body<256, 2>(cstage, a.fx[0], a.fW[0], a.fb[0], a.fo1[0], a.fo2[0],
                     a.fN[0], vb, a.fB[0]);
    return;
  }
  vb -= a.fB[0];
  if (vb < a.fB[1]) {
    fc1_body<128, 1>(cstage, a.fx[1], a.fW[1], a.fb[1], a.fo1[1], a.fo2[1],
                     a.fN[1], vb, a.fB[1]);
    return;
  }
  vb -= a.fB[1];
#pragma unroll
  for (int r = 0; r < 4; r++) {
    if (vb < a.nb[r]) {
      scatter_body(a.src[r], a.dst[r], a.w[r], a.cur[r], a.cw[r], a.E[r], vb);
      return;
    }
    vb -= a.nb[r];
  }
}

// Wave-per-node SPMM over 2 relations, bf16 rows (256B): 16 lanes x 16B per row.
// 16 edges per wave-iteration (4 per 16-lane slot). Edge stream + rel output NT.
__global__ __launch_bounds__(256) void spmm2_kernel(
    const ushort_t* __restrict__ xself,
    const float* __restrict__ d0, const float* __restrict__ d1,
    const ushort_t* __restrict__ h0, const ushort_t* __restrict__ h1,
    const int* __restrict__ rp0, const i32x2* __restrict__ cw0,
    const int* __restrict__ rp1, const i32x2* __restrict__ cw1,
    ushort_t* __restrict__ rel, int N) {
  int tid = threadIdx.x;
  int lane = tid & 63, wid = tid >> 6;
  int fg = lane & 15;
  int eslot = lane >> 4;
  int n = blockIdx.x * 4 + wid;
  if (n >= N) return;
  float xf[8];
  unpack8(*(const u32x4*)(xself + (size_t)n * 128 + fg * 8), xf);
#pragma unroll
  for (int srel = 0; srel < 2; srel++) {
    const float sd = srel ? d1[n] : d0[n];
    const int* rp = srel ? rp1 : rp0;
    const i32x2* cw = srel ? cw1 : cw0;
    const ushort_t* h = srel ? h1 : h0;
    float acc[8];
#pragma unroll
    for (int t = 0; t < 8; t++) acc[t] = 0.f;
    int beg = rp[n], end = rp[n + 1];
    for (int cb = beg; cb < end; cb += 64) {
      int m = end - cb; if (m > 64) m = 64;
      int creg = 0, wbits = 0;
      if (lane < m) {
        i32x2 p = __builtin_nontemporal_load(&cw[cb + lane]);
        creg = p.x; wbits = p.y;
      }
      int i = 0;
      for (; i + 16 <= m; i += 16) {
        int e0 = i + eslot, e1 = i + 4 + eslot, e2 = i + 8 + eslot, e3 = i + 12 + eslot;
        int   c0 = __shfl(creg, e0), c1 = __shfl(creg, e1);
        int   c2 = __shfl(creg, e2), c3 = __shfl(creg, e3);
        float v0 = i2f(__shfl(wbits, e0)), v1 = i2f(__shfl(wbits, e1));
        float v2 = i2f(__shfl(wbits, e2)), v3 = i2f(__shfl(wbits, e3));
        u32x4 g0 = *(const u32x4*)(h + (size_t)c0 * 128 + fg * 8);
        u32x4 g1 = *(const u32x4*)(h + (size_t)c1 * 128 + fg * 8);
        u32x4 g2 = *(const u32x4*)(h + (size_t)c2 * 128 + fg * 8);
        u32x4 g3 = *(const u32x4*)(h + (size_t)c3 * 128 + fg * 8);
        float hf[8];
        unpack8(g0, hf);
#pragma unroll
        for (int t = 0; t < 8; t++) acc[t] = fmaf(v0, hf[t], acc[t]);
        unpack8(g1, hf);
#pragma unroll
        for (int t = 0; t < 8; t++) acc[t] = fmaf(v1, hf[t], acc[t]);
        unpack8(g2, hf);
#pragma unroll
        for (int t = 0; t < 8; t++) acc[t] = fmaf(v2, hf[t], acc[t]);
        unpack8(g3, hf);
#pragma unroll
        for (int t = 0; t < 8; t++) acc[t] = fmaf(v3, hf[t], acc[t]);
      }
      for (; i < m; i += 4) {
        int e = i + eslot;
        int   c = __shfl(creg, e & 63);
        float v = i2f(__shfl(wbits, e & 63));
        if (e < m) {
          u32x4 g = *(const u32x4*)(h + (size_t)c * 128 + fg * 8);
          float hf[8];
          unpack8(g, hf);
#pragma unroll
          for (int t = 0; t < 8; t++) acc[t] = fmaf(v, hf[t], acc[t]);
        }
      }
    }
#pragma unroll
    for (int t = 0; t < 8; t++) {
      acc[t] += __shfl_xor(acc[t], 16);
      acc[t] += __shfl_xor(acc[t], 32);
    }
    if (eslot == 0) {
#pragma unroll
      for (int t = 0; t < 8; t++) acc[t] = fmaf(sd, xf[t], acc[t]);
      __builtin_nontemporal_store(pack8(acc),
          (u32x4*)(rel + (size_t)n * 256 + srel * 128 + fg * 8));
    }
  }
}

// HAN scores via bf16 MFMA. W1 held in registers as B-frags; A-frags NT bf16 loads.
__global__ __launch_bounds__(256) void score_mfma_kernel(
    const ushort_t* __restrict__ rel,   // [N,2,128] bf16
    const float* __restrict__ W1,       // [128,128] (k-major)
    const float* __restrict__ b1, const float* __restrict__ w2,
    float* __restrict__ s_out, int N, int nwaves) {
  int tid = threadIdx.x;
  int lane = tid & 63;
  int gw = blockIdx.x * 4 + (tid >> 6);
  int r = lane & 15;
  int kg = lane >> 4;
  bf16x8 bfr[8][4];
#pragma unroll
  for (int jt = 0; jt < 8; jt++) {
    int j = jt * 16 + r;
#pragma unroll
    for (int kt = 0; kt < 4; kt++) {
      int k0 = kt * 32 + kg * 8;
      bf16x8 v;
#pragma unroll
      for (int t = 0; t < 8; t++) v[t] = (short)f2bf(W1[(size_t)(k0 + t) * 128 + j]);
      bfr[jt][kt] = v;
    }
  }
  float b1v[8], w2v[8];
#pragma unroll
  for (int jt = 0; jt < 8; jt++) { b1v[jt] = b1[jt * 16 + r]; w2v[jt] = w2[jt * 16 + r]; }
  float s0 = 0.f, s1 = 0.f;
  int ntiles = (N + 15) >> 4;
  for (int tile = gw; tile < ntiles; tile += nwaves) {
    int n0 = tile * 16;
    int nodeA = n0 + r;
    size_t base = (size_t)((nodeA < N) ? nodeA : 0) * 256;
#pragma unroll
    for (int sub = 0; sub < 2; sub++) {
      bf16x8 afr[4];
#pragma unroll
      for (int kt = 0; kt < 4; kt++)
        afr[kt] = __builtin_nontemporal_load(
            (const bf16x8*)(rel + base + sub * 128 + kt * 32 + kg * 8));
      f32x4 acc[8];
#pragma unroll
      for (int jt = 0; jt < 8; jt++) acc[jt] = (f32x4){0.f, 0.f, 0.f, 0.f};
#pragma unroll
      for (int jt = 0; jt < 8; jt++)
#pragma unroll
        for (int kt = 0; kt < 4; kt++)
          acc[jt] = __builtin_amdgcn_mfma_f32_16x16x32_bf16(afr[kt], bfr[jt][kt], acc[jt], 0, 0, 0);
      float sacc = 0.f;
#pragma unroll
      for (int jt = 0; jt < 8; jt++) {
#pragma unroll
        for (int reg = 0; reg < 4; reg++) {
          int nm = n0 + kg * 4 + reg;
          if (nm < N) sacc += w2v[jt] * tanhf(acc[jt][reg] + b1v[jt]);
        }
      }
      if (sub == 0) s0 += sacc; else s1 += sacc;
    }
  }
#pragma unroll
  for (int m = 32; m >= 1; m >>= 1) { s0 += __shfl_xor(s0, m); s1 += __shfl_xor(s1, m); }
  if (lane == 0) { atomicAdd(&s_out[0], s0); atomicAdd(&s_out[1], s1); }
}

// h[n,:] = beta0*rel[n,0,:] + beta1*rel[n,1,:]; NT rel reads, cached h store.
__global__ void combine_kernel(const ushort_t* __restrict__ rel, const float* __restrict__ s,
                               ushort_t* __restrict__ h, int N, float invN) {
  int i = blockIdx.x * blockDim.x + threadIdx.x;
  if (i >= N * 16) return;
  float m0 = s[0] * invN, m1 = s[1] * invN;
  float mx = fmaxf(m0, m1);
  float e0 = expf(m0 - mx), e1 = expf(m1 - mx);
  float inv = 1.f / (e0 + e1);
  float be0 = e0 * inv, be1 = e1 * inv;
  int n = i >> 4, q = i & 15;
  float f0[8], f1[8], o[8];
  unpack8(__builtin_nontemporal_load((const u32x4*)(rel + (size_t)n * 256 + q * 8)), f0);
  unpack8(__builtin_nontemporal_load((const u32x4*)(rel + (size_t)n * 256 + 128 + q * 8)), f1);
#pragma unroll
  for (int t = 0; t < 8; t++) o[t] = be0 * f0[t] + be1 * f1[t];
  *(u32x4*)(h + (size_t)n * 128 + q * 8) = pack8(o);
}

// fc2 via bf16 MFMA: out = h @ W2(128x64) + b2.
__global__ __launch_bounds__(256) void fc2_mfma_kernel(
    const ushort_t* __restrict__ h,     // [N,128] bf16
    const float* __restrict__ W,        // [128,64]
    const float* __restrict__ b,        // [64]
    float* __restrict__ out, int N, int nwaves) {
  int tid = threadIdx.x;
  int lane = tid & 63;
  int gw = blockIdx.x * 4 + (tid >> 6);
  int r = lane & 15, kg = lane >> 4;
  bf16x8 bfr[4][4];
#pragma unroll
  for (int jt = 0; jt < 4; jt++) {
    int j = jt * 16 + r;
#pragma unroll
    for (int kt = 0; kt < 4; kt++) {
      int k0 = kt * 32 + kg * 8;
      bf16x8 v;
#pragma unroll
      for (int t = 0; t < 8; t++) v[t] = (short)f2bf(W[(size_t)(k0 + t) * 64 + j]);
      bfr[jt][kt] = v;
    }
  }
  float bv[4];
#pragma unroll
  for (int jt = 0; jt < 4; jt++) bv[jt] = b[jt * 16 + r];
  int ntiles = (N + 15) >> 4;
  for (int tile = gw; tile < ntiles; tile += nwaves) {
    int n0 = tile * 16;
    int nodeA = n0 + r;
    const ushort_t* hrow = h + (size_t)((nodeA < N) ? nodeA : 0) * 128;
    bf16x8 afr[4];
#pragma unroll
    for (int kt = 0; kt < 4; kt++)
      afr[kt] = *(const bf16x8*)(hrow + kt * 32 + kg * 8);
    f32x4 acc[4];
#pragma unroll
    for (int jt = 0; jt < 4; jt++) acc[jt] = (f32x4){0.f, 0.f, 0.f, 0.f};
#pragma unroll
    for (int jt = 0; jt < 4; jt++)
#pragma unroll
      for (int kt = 0; kt < 4; kt++)
        acc[jt] = __builtin_amdgcn_mfma_f32_16x16x32_bf16(afr[kt], bfr[jt][kt], acc[jt], 0, 0, 0);
#pragma unroll
    for (int jt = 0; jt < 4; jt++)
#pragma unroll
      for (int reg = 0; reg < 4; reg++) {
        int n = n0 + kg * 4 + reg;
        if (n < N) out[(size_t)n * 64 + jt * 16 + r] = acc[jt][reg] + bv[jt];
      }
  }
}

extern "C" void kernel_launch(void* const* d_in, const int* in_sizes, int n_in,
                              void* d_out, int out_size, void* d_ws, size_t ws_size,
                              hipStream_t stream) {
  const float* x_paper  = (const float*)d_in[0];
  const float* x_author = (const float*)d_in[1];
  const float* fc1p_W = (const float*)d_in[2];
  const float* fc1p_b = (const float*)d_in[3];
  const float* fc1a_W = (const float*)d_in[4];
  const float* fc1a_b = (const float*)d_in[5];
  const float* fc2_W  = (const float*)d_in[6];
  const float* fc2_b  = (const float*)d_in[7];
  const float* semW1  = (const float*)d_in[8];
  const float* semb1  = (const float*)d_in[9];
  const float* semw2  = (const float*)d_in[10];
  const float* d_pp = (const float*)d_in[11];
  const float* d_pa = (const float*)d_in[12];
  const float* d_ap = (const float*)d_in[13];
  const float* d_aa = (const float*)d_in[14];
  const float* w_pp = (const float*)d_in[15];
  const float* w_pa = (const float*)d_in[16];
  const float* w_ap = (const float*)d_in[17];
  const float* w_aa = (const float*)d_in[18];
  const int* src_pp = (const int*)d_in[19];
  const int* dst_pp = (const int*)d_in[20];
  const int* src_pa = (const int*)d_in[21];
  const int* dst_pa = (const int*)d_in[22];
  const int* src_ap = (const int*)d_in[23];
  const int* dst_ap = (const int*)d_in[24];
  const int* src_aa = (const int*)d_in[25];
  const int* dst_aa = (const int*)d_in[26];

  const int Np = in_sizes[11];
  const int Na = in_sizes[13];
  const int E[4] = { in_sizes[15], in_sizes[16], in_sizes[17], in_sizes[18] };
  const int Nmax = (Np > Na) ? Np : Na;

  char* base = (char*)d_ws;
  size_t off = 0;
  ushort_t* xp = (ushort_t*)(base + off); off += (size_t)Np * 128 * 2;
  ushort_t* xa = (ushort_t*)(base + off); off += (size_t)Na * 128 * 2;
  ushort_t* hp = (ushort_t*)(base + off); off += (size_t)Np * 128 * 2;
  ushort_t* ha = (ushort_t*)(base + off); off += (size_t)Na * 128 * 2;
  ushort_t* rel = (ushort_t*)(base + off); off += (size_t)Nmax * 256 * 2;
  float* ssum = (float*)(base + off); off += 32 * 4;
  int* cnt  = (int*)(base + off); off += (size_t)(2 * Np + 2 * Na) * 4;
  int* rpB  = (int*)(base + off); off += (size_t)(2 * (Np + 1) + 2 * (Na + 1)) * 4;
  int* curB = (int*)(base + off); off += (size_t)(2 * Np + 2 * Na) * 4;
  size_t Esum = (size_t)E[0] + E[1] + E[2] + E[3];
  off = (off + 15) & ~(size_t)15;
  i32x2* cwB = (i32x2*)(base + off); off += Esum * 8;
  (void)ws_size; (void)n_in; (void)out_size;

  int* cnt_r[4] = { cnt, cnt + Np, cnt + (size_t)2 * Np, cnt + (size_t)2 * Np + Na };
  int* rp_r[4]  = { rpB, rpB + (Np + 1), rpB + (size_t)2 * (Np + 1),
                    rpB + (size_t)2 * (Np + 1) + (Na + 1) };
  int* cur_r[4] = { curB, curB + Np, curB + (size_t)2 * Np, curB + (size_t)2 * Np + Na };
  size_t eoff[4] = { 0, (size_t)E[0], (size_t)E[0] + E[1], (size_t)E[0] + E[1] + E[2] };
  i32x2* cw_r[4];
  for (int r = 0; r < 4; r++) cw_r[r] = cwB + eoff[r];

  const int* srcs[4]    = { src_pp, src_pa, src_ap, src_aa };
  const int* dsts[4]    = { dst_pp, dst_pa, dst_ap, dst_aa };
  const float* wedge[4] = { w_pp, w_pa, w_ap, w_aa };

  int Z = 32 + 2 * Np + 2 * Na;
  zero_kernel<<<(Z + 255) / 256, 256, 0, stream>>>(ssum, Z);

  // merged histogram over all 4 relations
  Hist4Args ha_args;
  int hist_blocks = 0;
  for (int r = 0; r < 4; r++) {
    ha_args.dst[r] = dsts[r];
    ha_args.cnt[r] = cnt_r[r];
    ha_args.E[r] = E[r];
    ha_args.nb[r] = (E[r] + 255) / 256;
    hist_blocks += ha_args.nb[r];
  }
  hist4_kernel<<<hist_blocks, 256, 0, stream>>>(ha_args);

  scan4_kernel<<<4, 1024, 0, stream>>>(cnt, rpB, curB, Np, Na);

  // fused: scatter (4 relations) + fc1p + fc1a
  BuildArgs ba;
  ba.fx[0] = x_paper;  ba.fW[0] = fc1p_W; ba.fb[0] = fc1p_b;
  ba.fo1[0] = xp; ba.fo2[0] = hp; ba.fN[0] = Np; ba.fB[0] = 256;
  ba.fx[1] = x_author; ba.fW[1] = fc1a_W; ba.fb[1] = fc1a_b;
  ba.fo1[1] = xa; ba.fo2[1] = ha; ba.fN[1] = Na; ba.fB[1] = 256;
  int build_blocks = ba.fB[0] + ba.fB[1];
  for (int r = 0; r < 4; r++) {
    ba.src[r] = srcs[r]; ba.dst[r] = dsts[r]; ba.w[r] = wedge[r];
    ba.cur[r] = cur_r[r]; ba.cw[r] = cw_r[r]; ba.E[r] = E[r];
    ba.nb[r] = (E[r] + 255) / 256;
    build_blocks += ba.nb[r];
  }
  build_kernel<<<build_blocks, 256, 0, stream>>>(ba);

  const int SCORE_BLOCKS = 256;
  const int SCORE_WAVES = SCORE_BLOCKS * 4;

  for (int i = 0; i < 5; i++) {
    // paper: pp (gather h_p), pa (gather h_a)
    float* sp = ssum + (size_t)(i * 2 + 0) * 2;
    spmm2_kernel<<<(Np + 3) / 4, 256, 0, stream>>>(xp, d_pp, d_pa, hp, ha,
        rp_r[0], cw_r[0], rp_r[1], cw_r[1], rel, Np);
    score_mfma_kernel<<<SCORE_BLOCKS, 256, 0, stream>>>(rel,
        semW1 + (size_t)(i * 2 + 0) * 16384, semb1 + (size_t)(i * 2 + 0) * 128,
        semw2 + (size_t)(i * 2 + 0) * 128, sp, Np, SCORE_WAVES);
    combine_kernel<<<(Np * 16 + 255) / 256, 256, 0, stream>>>(rel, sp, hp, Np, 1.f / Np);

    // author: ap (gather new h_p), aa (gather h_a).
    // Final hop's author output is dead (only h_p feeds fc2) -> skip, matching JAX DCE.
    if (i < 4) {
      float* sa = ssum + (size_t)(i * 2 + 1) * 2;
      spmm2_kernel<<<(Na + 3) / 4, 256, 0, stream>>>(xa, d_ap, d_aa, hp, ha,
          rp_r[2], cw_r[2], rp_r[3], cw_r[3], rel, Na);
      score_mfma_kernel<<<SCORE_BLOCKS, 256, 0, stream>>>(rel,
          semW1 + (size_t)(i * 2 + 1) * 16384, semb1 + (size_t)(i * 2 + 1) * 128,
          semw2 + (size_t)(i * 2 + 1) * 128, sa, Na, SCORE_WAVES);
      combine_kernel<<<(Na * 16 + 255) / 256, 256, 0, stream>>>(rel, sa, ha, Na, 1.f / Na);
    }
  }

  fc2_mfma_kernel<<<256, 256, 0, stream>>>(hp, fc2_W, fc2_b, (float*)d_out, Np, 1024);
}